// Round 11
// baseline (165.954 us; speedup 1.0000x reference)
//
#include <hip/hip_runtime.h>

#define NN   50000
#define NE   200000
#define INC  16
#define HIDC 32
#define EDGED 8
#define OUTC 32
#define MLPH 128
#define NACT 32

#define NPART 196   // ceil(NN / 256)

// ---- degree histogram ----
__global__ __launch_bounds__(256) void hist_kernel(const int* __restrict__ edst,
                                                   int* __restrict__ deg) {
    int e = blockIdx.x * blockDim.x + threadIdx.x;
    if (e < NE) atomicAdd(&deg[edst[e]], 1);
}

// ---- scan pass 1: per-block sums ----
__global__ __launch_bounds__(256) void partial_kernel(const int* __restrict__ deg,
                                                      int* __restrict__ partials) {
    __shared__ int sm[256];
    int t = threadIdx.x, i = blockIdx.x * 256 + t;
    sm[t] = (i < NN) ? deg[i] : 0;
    __syncthreads();
    #pragma unroll
    for (int off = 128; off > 0; off >>= 1) {
        if (t < off) sm[t] += sm[t + off];
        __syncthreads();
    }
    if (t == 0) partials[blockIdx.x] = sm[0];
}

// ---- scan pass 2: exclusive scan of 196 partials ----
__global__ __launch_bounds__(256) void scan_partials_kernel(const int* __restrict__ partials,
                                                            int* __restrict__ poff) {
    __shared__ int sm[256];
    int t = threadIdx.x;
    sm[t] = (t < NPART) ? partials[t] : 0;
    __syncthreads();
    for (int off = 1; off < 256; off <<= 1) {
        int v = (t >= off) ? sm[t - off] : 0;
        __syncthreads();
        sm[t] += v;
        __syncthreads();
    }
    poff[t] = (t == 0) ? 0 : sm[t - 1];
}

// ---- scan pass 3: block-local scan + base -> row_off ----
__global__ __launch_bounds__(256) void rowoff_kernel(const int* __restrict__ deg,
                                                     const int* __restrict__ poff,
                                                     int* __restrict__ row_off) {
    __shared__ int sm[256];
    int t = threadIdx.x, i = blockIdx.x * 256 + t;
    int d = (i < NN) ? deg[i] : 0;
    sm[t] = d;
    __syncthreads();
    for (int off = 1; off < 256; off <<= 1) {
        int v = (t >= off) ? sm[t - off] : 0;
        __syncthreads();
        sm[t] += v;
        __syncthreads();
    }
    int excl = sm[t] - d + poff[blockIdx.x];
    if (i < NN) {
        row_off[i] = excl;
        if (i == NN - 1) row_off[NN] = excl + d;   // == NE
    }
}

// ---- build position map: epos[e] = sorted position ----
__global__ __launch_bounds__(256) void build_pos_kernel(const int* __restrict__ edst,
                                                        const int* __restrict__ row_off,
                                                        int* __restrict__ cursor,
                                                        int* __restrict__ epos) {
    int e = blockIdx.x * blockDim.x + threadIdx.x;
    if (e < NE) {
        int dst = edst[e];
        epos[e] = row_off[dst] + atomicAdd(&cursor[dst], 1);
    }
}

// ---- edge kernel: quad per edge-group, 4 edges/thread (register-tiled
//      weight reuse). Lane l owns channels {4l..4l+3, 16+4l..16+4l+3} so
//      each store instruction writes COMPLETE 64-B sectors -> no write
//      amplification even though rows go to dst-sorted (scattered) slots. ----
__global__ __launch_bounds__(256, 3) void edge_q4_kernel(
    const float* __restrict__ x,
    const int*   __restrict__ esrc,
    const float* __restrict__ ea,
    const float* __restrict__ We,        // [8][512] original layout
    const float* __restrict__ be,        // [512]
    const int*   __restrict__ epos,      // [NE] sorted position
    float*       __restrict__ sorted_msg) // [NE][32] dst-sorted rows
{
    __shared__ float sWe2[4 * 1032];  // [l][(i*8+cc)*8 + d]
    __shared__ float sbe2[4 * 132];   // [l][i*8+cc]
    int t = threadIdx.x;
    // destination-ordered staging: consecutive lanes -> consecutive words
    for (int idx = t; idx < 4 * 1032; idx += 256) {
        int l = idx / 1032, r = idx - l * 1032;
        float v = 0.f;
        if (r < 1024) {
            int d = r & 7, icc = r >> 3;
            int i = icc >> 3, cc = icc & 7;
            int h = ((cc & 4) << 2) + l * 4 + (cc & 3);   // channel
            v = We[d * 512 + i * 32 + h];
        }
        sWe2[idx] = v;
    }
    for (int idx = t; idx < 4 * 132; idx += 256) {
        int l = idx / 132, r = idx - l * 132;
        float v = 0.f;
        if (r < 128) {
            int i = r >> 3, cc = r & 7;
            int h = ((cc & 4) << 2) + l * 4 + (cc & 3);
            v = be[i * 32 + h];
        }
        sbe2[idx] = v;
    }
    __syncthreads();

    int Q = blockIdx.x * 64 + (t >> 2);
    int l = t & 3;
    if (Q >= NE / 4) return;

    int e0 = Q, e1 = Q + 50000, e2 = Q + 100000, e3 = Q + 150000;
    int s0 = esrc[e0], s1 = esrc[e1], s2 = esrc[e2], s3 = esrc[e3];
    int p0 = epos[e0], p1 = epos[e1], p2 = epos[e2], p3 = epos[e3];

    float ea0[8], ea1[8], ea2[8], ea3[8];
    {
        const float4* p;
        float4 a, b;
        p = reinterpret_cast<const float4*>(ea) + (size_t)e0 * 2; a = p[0]; b = p[1];
        ea0[0]=a.x; ea0[1]=a.y; ea0[2]=a.z; ea0[3]=a.w; ea0[4]=b.x; ea0[5]=b.y; ea0[6]=b.z; ea0[7]=b.w;
        p = reinterpret_cast<const float4*>(ea) + (size_t)e1 * 2; a = p[0]; b = p[1];
        ea1[0]=a.x; ea1[1]=a.y; ea1[2]=a.z; ea1[3]=a.w; ea1[4]=b.x; ea1[5]=b.y; ea1[6]=b.z; ea1[7]=b.w;
        p = reinterpret_cast<const float4*>(ea) + (size_t)e2 * 2; a = p[0]; b = p[1];
        ea2[0]=a.x; ea2[1]=a.y; ea2[2]=a.z; ea2[3]=a.w; ea2[4]=b.x; ea2[5]=b.y; ea2[6]=b.z; ea2[7]=b.w;
        p = reinterpret_cast<const float4*>(ea) + (size_t)e3 * 2; a = p[0]; b = p[1];
        ea3[0]=a.x; ea3[1]=a.y; ea3[2]=a.z; ea3[3]=a.w; ea3[4]=b.x; ea3[5]=b.y; ea3[6]=b.z; ea3[7]=b.w;
    }

    float m0[8], m1[8], m2[8], m3[8];
    #pragma unroll
    for (int c = 0; c < 8; ++c) { m0[c]=0.f; m1[c]=0.f; m2[c]=0.f; m3[c]=0.f; }

    const float* wl = sWe2 + l * 1032;
    const float* bl = sbe2 + l * 132;
    const float4* xp0 = reinterpret_cast<const float4*>(x) + (size_t)s0 * 4;
    const float4* xp1 = reinterpret_cast<const float4*>(x) + (size_t)s1 * 4;
    const float4* xp2 = reinterpret_cast<const float4*>(x) + (size_t)s2 * 4;
    const float4* xp3 = reinterpret_cast<const float4*>(x) + (size_t)s3 * 4;

    for (int i4 = 0; i4 < 4; ++i4) {        // rolled: keeps code I$-sized
        float4 xv0 = xp0[i4], xv1 = xp1[i4], xv2 = xp2[i4], xv3 = xp3[i4];
        float xs0[4] = {xv0.x, xv0.y, xv0.z, xv0.w};
        float xs1[4] = {xv1.x, xv1.y, xv1.z, xv1.w};
        float xs2[4] = {xv2.x, xv2.y, xv2.z, xv2.w};
        float xs3[4] = {xv3.x, xv3.y, xv3.z, xv3.w};
        const float* wb4 = wl + i4 * 256;
        const float* bb4 = bl + i4 * 32;
        #pragma unroll
        for (int ii = 0; ii < 4; ++ii) {
            const float* wbase = wb4 + ii * 64;
            const float* bbase = bb4 + ii * 8;
            float xi0 = xs0[ii], xi1 = xs1[ii], xi2 = xs2[ii], xi3 = xs3[ii];
            #pragma unroll
            for (int cc = 0; cc < 8; ++cc) {
                const float* wr = wbase + cc * 8;
                float bv = bbase[cc];
                float w0 = bv, w1 = bv, w2 = bv, w3 = bv;
                #pragma unroll
                for (int d = 0; d < 8; ++d) {
                    float wd = wr[d];
                    w0 = fmaf(ea0[d], wd, w0);
                    w1 = fmaf(ea1[d], wd, w1);
                    w2 = fmaf(ea2[d], wd, w2);
                    w3 = fmaf(ea3[d], wd, w3);
                }
                w0 = fmaxf(w0, 0.f); w1 = fmaxf(w1, 0.f);
                w2 = fmaxf(w2, 0.f); w3 = fmaxf(w3, 0.f);
                m0[cc] = fmaf(xi0, w0, m0[cc]);
                m1[cc] = fmaf(xi1, w1, m1[cc]);
                m2[cc] = fmaf(xi2, w2, m2[cc]);
                m3[cc] = fmaf(xi3, w3, m3[cc]);
            }
        }
    }

    // slots 0..3 = channels 4l..4l+3 -> float offset l*4 (bytes [l*16, l*16+16))
    // slots 4..7 = channels 16+4l..   -> float offset 16+l*4 (second 64-B sector)
    float4* o;
    o = reinterpret_cast<float4*>(sorted_msg + (size_t)p0 * 32 + l * 4);
    o[0] = make_float4(m0[0], m0[1], m0[2], m0[3]);
    o[4] = make_float4(m0[4], m0[5], m0[6], m0[7]);   // +16 floats = 4 float4s
    o = reinterpret_cast<float4*>(sorted_msg + (size_t)p1 * 32 + l * 4);
    o[0] = make_float4(m1[0], m1[1], m1[2], m1[3]);
    o[4] = make_float4(m1[4], m1[5], m1[6], m1[7]);
    o = reinterpret_cast<float4*>(sorted_msg + (size_t)p2 * 32 + l * 4);
    o[0] = make_float4(m2[0], m2[1], m2[2], m2[3]);
    o[4] = make_float4(m2[4], m2[5], m2[6], m2[7]);
    o = reinterpret_cast<float4*>(sorted_msg + (size_t)p3 * 32 + l * 4);
    o[0] = make_float4(m3[0], m3[1], m3[2], m3[3]);
    o[4] = make_float4(m3[4], m3[5], m3[6], m3[7]);
}

// ---- feat kernel: 4 lanes/node; CONTIGUOUS sorted_msg stream (no eperm).
//      Lane l owns channels {4l..4l+3, 16+4l..16+4l+3}. ----
__global__ __launch_bounds__(256, 4) void feat_kernel(
    const float* __restrict__ x,
    const float* __restrict__ sorted_msg,  // [NE][32] dst-sorted
    const int*   __restrict__ row_off,
    const float* __restrict__ Wroot,   // [16][32]
    const float* __restrict__ bconv,
    const float* __restrict__ gamma,
    const float* __restrict__ beta,
    const float* __restrict__ Wlin,    // [32][32]
    const float* __restrict__ blin,
    float* __restrict__ feat)          // [NN][32]
{
    int tid = blockIdx.x * 256 + threadIdx.x;
    int n = tid >> 2;
    int l = tid & 3;
    if (n >= NN) return;
    int o1 = l * 4;        // float offset of first slice
    int o2 = 16 + l * 4;   // float offset of second slice

    float h8[8];
    {
        const float4 a = *reinterpret_cast<const float4*>(bconv + o1);
        const float4 b = *reinterpret_cast<const float4*>(bconv + o2);
        h8[0]=a.x; h8[1]=a.y; h8[2]=a.z; h8[3]=a.w;
        h8[4]=b.x; h8[5]=b.y; h8[6]=b.z; h8[7]=b.w;
    }

    int start = row_off[n], end = row_off[n + 1];
    for (int k = start; k < end; ++k) {
        const float* row = sorted_msg + (size_t)k * 32;
        float4 a = *reinterpret_cast<const float4*>(row + o1);
        float4 b = *reinterpret_cast<const float4*>(row + o2);
        h8[0]+=a.x; h8[1]+=a.y; h8[2]+=a.z; h8[3]+=a.w;
        h8[4]+=b.x; h8[5]+=b.y; h8[6]+=b.z; h8[7]+=b.w;
    }

    const float4* x4 = reinterpret_cast<const float4*>(x) + (size_t)n * 4;
    #pragma unroll
    for (int i4 = 0; i4 < 4; ++i4) {
        float4 xv = x4[i4];
        float xsub[4] = {xv.x, xv.y, xv.z, xv.w};
        #pragma unroll
        for (int ii = 0; ii < 4; ++ii) {
            const float* wr = Wroot + (i4 * 4 + ii) * HIDC;
            float4 a = *reinterpret_cast<const float4*>(wr + o1);
            float4 b = *reinterpret_cast<const float4*>(wr + o2);
            float xi = xsub[ii];
            h8[0]=fmaf(xi,a.x,h8[0]); h8[1]=fmaf(xi,a.y,h8[1]);
            h8[2]=fmaf(xi,a.z,h8[2]); h8[3]=fmaf(xi,a.w,h8[3]);
            h8[4]=fmaf(xi,b.x,h8[4]); h8[5]=fmaf(xi,b.y,h8[5]);
            h8[6]=fmaf(xi,b.z,h8[6]); h8[7]=fmaf(xi,b.w,h8[7]);
        }
    }

    // LayerNorm (quad butterfly on scalars) + ReLU
    float s = ((h8[0]+h8[1])+(h8[2]+h8[3])) + ((h8[4]+h8[5])+(h8[6]+h8[7]));
    s += __shfl_xor(s, 1);
    s += __shfl_xor(s, 2);
    float mu = s * (1.f / HIDC);
    float v = 0.f;
    #pragma unroll
    for (int c = 0; c < 8; ++c) { float d = h8[c] - mu; v = fmaf(d, d, v); }
    v += __shfl_xor(v, 1);
    v += __shfl_xor(v, 2);
    float rstd = rsqrtf(v * (1.f / HIDC) + 1e-5f);
    {
        float4 g0 = *reinterpret_cast<const float4*>(gamma + o1);
        float4 g1 = *reinterpret_cast<const float4*>(gamma + o2);
        float4 b0 = *reinterpret_cast<const float4*>(beta + o1);
        float4 b1 = *reinterpret_cast<const float4*>(beta + o2);
        float gs[8] = {g0.x,g0.y,g0.z,g0.w,g1.x,g1.y,g1.z,g1.w};
        float bs[8] = {b0.x,b0.y,b0.z,b0.w,b1.x,b1.y,b1.z,b1.w};
        #pragma unroll
        for (int c = 0; c < 8; ++c)
            h8[c] = fmaxf(fmaf((h8[c] - mu) * rstd, gs[c], bs[c]), 0.f);
    }

    // feat slices: broadcast h via width-4 shuffles; k = (c>>2)*16+srcl*4+(c&3)
    float f8[8];
    {
        float4 a = *reinterpret_cast<const float4*>(blin + o1);
        float4 b = *reinterpret_cast<const float4*>(blin + o2);
        f8[0]=a.x; f8[1]=a.y; f8[2]=a.z; f8[3]=a.w;
        f8[4]=b.x; f8[5]=b.y; f8[6]=b.z; f8[7]=b.w;
    }
    #pragma unroll
    for (int srcl = 0; srcl < 4; ++srcl) {
        #pragma unroll
        for (int c = 0; c < 8; ++c) {
            float hv = __shfl(h8[c], srcl, 4);
            int k = ((c & 4) << 2) + srcl * 4 + (c & 3);   // channel of h8[c]@srcl
            const float* wr = Wlin + k * OUTC;
            float4 a = *reinterpret_cast<const float4*>(wr + o1);
            float4 b = *reinterpret_cast<const float4*>(wr + o2);
            f8[0]=fmaf(hv,a.x,f8[0]); f8[1]=fmaf(hv,a.y,f8[1]);
            f8[2]=fmaf(hv,a.z,f8[2]); f8[3]=fmaf(hv,a.w,f8[3]);
            f8[4]=fmaf(hv,b.x,f8[4]); f8[5]=fmaf(hv,b.y,f8[5]);
            f8[6]=fmaf(hv,b.z,f8[6]); f8[7]=fmaf(hv,b.w,f8[7]);
        }
    }

    float* orow = feat + (size_t)n * OUTC;
    *reinterpret_cast<float4*>(orow + o1) = make_float4(f8[0], f8[1], f8[2], f8[3]);
    *reinterpret_cast<float4*>(orow + o2) = make_float4(f8[4], f8[5], f8[6], f8[7]);
}

// ---- q_head: quad per node-pair, 2 nodes/thread (unchanged from R10) ----
__global__ __launch_bounds__(256, 3) void qhead_kernel(
    const float* __restrict__ feat,    // [NN][32]
    const float* __restrict__ Wq1,     // [32][128] original layout
    const float* __restrict__ bq1,
    const float* __restrict__ Wq2,     // [128][32]
    const float* __restrict__ bq2,
    float* __restrict__ out)
{
    __shared__ float sw1[4 * 1032];    // [l][k*32+j], stagger 1032
    int t = threadIdx.x;
    for (int w = t; w < 4096; w += 256) {
        int k = w >> 7, m = w & 127, l = m >> 5, j = m & 31;
        sw1[l * 1032 + k * 32 + j] = Wq1[w];
    }
    __syncthreads();

    int gid = blockIdx.x * 256 + t;
    int p = gid >> 2;
    int l = gid & 3;
    if (p >= NN / 2) return;
    int n0 = p * 2, n1 = p * 2 + 1;

    float f0[OUTC], f1[OUTC];
    {
        const float4* a4 = reinterpret_cast<const float4*>(feat + (size_t)n0 * 32);
        const float4* b4 = reinterpret_cast<const float4*>(feat + (size_t)n1 * 32);
        #pragma unroll
        for (int i = 0; i < 8; ++i) {
            float4 a = a4[i], b = b4[i];
            f0[i*4+0]=a.x; f0[i*4+1]=a.y; f0[i*4+2]=a.z; f0[i*4+3]=a.w;
            f1[i*4+0]=b.x; f1[i*4+1]=b.y; f1[i*4+2]=b.z; f1[i*4+3]=b.w;
        }
    }

    float acc0[32], acc1[32];
    {
        const float4* b4 = reinterpret_cast<const float4*>(bq1 + l * 32);
        #pragma unroll
        for (int j4 = 0; j4 < 8; ++j4) {
            float4 b = b4[j4];
            acc0[j4*4+0]=b.x; acc0[j4*4+1]=b.y; acc0[j4*4+2]=b.z; acc0[j4*4+3]=b.w;
            acc1[j4*4+0]=b.x; acc1[j4*4+1]=b.y; acc1[j4*4+2]=b.z; acc1[j4*4+3]=b.w;
        }
    }
    const float* w1 = sw1 + l * 1032;
    #pragma unroll
    for (int k = 0; k < 32; ++k) {
        float fk0 = f0[k], fk1 = f1[k];
        const float* wr = w1 + k * 32;
        #pragma unroll
        for (int j = 0; j < 32; ++j) {
            float wj = wr[j];
            acc0[j] = fmaf(fk0, wj, acc0[j]);
            acc1[j] = fmaf(fk1, wj, acc1[j]);
        }
    }
    #pragma unroll
    for (int j = 0; j < 32; ++j) {
        acc0[j] = fmaxf(acc0[j], 0.f);
        acc1[j] = fmaxf(acc1[j], 0.f);
    }

    float q0[8], q1[8];
    {
        const float4* b4 = reinterpret_cast<const float4*>(bq2 + l * 8);
        float4 a = b4[0], b = b4[1];
        q0[0]=a.x; q0[1]=a.y; q0[2]=a.z; q0[3]=a.w;
        q0[4]=b.x; q0[5]=b.y; q0[6]=b.z; q0[7]=b.w;
        #pragma unroll
        for (int c = 0; c < 8; ++c) q1[c] = q0[c];
    }
    #pragma unroll
    for (int srcl = 0; srcl < 4; ++srcl) {
        #pragma unroll
        for (int j = 0; j < 32; ++j) {
            float a0 = __shfl(acc0[j], srcl, 4);
            float a1 = __shfl(acc1[j], srcl, 4);
            int m = srcl * 32 + j;
            const float4* w2 = reinterpret_cast<const float4*>(Wq2 + m * NACT + l * 8);
            float4 wa = w2[0], wb = w2[1];
            q0[0]=fmaf(a0,wa.x,q0[0]); q0[1]=fmaf(a0,wa.y,q0[1]);
            q0[2]=fmaf(a0,wa.z,q0[2]); q0[3]=fmaf(a0,wa.w,q0[3]);
            q0[4]=fmaf(a0,wb.x,q0[4]); q0[5]=fmaf(a0,wb.y,q0[5]);
            q0[6]=fmaf(a0,wb.z,q0[6]); q0[7]=fmaf(a0,wb.w,q0[7]);
            q1[0]=fmaf(a1,wa.x,q1[0]); q1[1]=fmaf(a1,wa.y,q1[1]);
            q1[2]=fmaf(a1,wa.z,q1[2]); q1[3]=fmaf(a1,wa.w,q1[3]);
            q1[4]=fmaf(a1,wb.x,q1[4]); q1[5]=fmaf(a1,wb.y,q1[5]);
            q1[6]=fmaf(a1,wb.z,q1[6]); q1[7]=fmaf(a1,wb.w,q1[7]);
        }
    }

    float4* o;
    o = reinterpret_cast<float4*>(out + (size_t)n0 * NACT + l * 8);
    o[0] = make_float4(q0[0], q0[1], q0[2], q0[3]);
    o[1] = make_float4(q0[4], q0[5], q0[6], q0[7]);
    o = reinterpret_cast<float4*>(out + (size_t)n1 * NACT + l * 8);
    o[0] = make_float4(q1[0], q1[1], q1[2], q1[3]);
    o[1] = make_float4(q1[4], q1[5], q1[6], q1[7]);
}

extern "C" void kernel_launch(void* const* d_in, const int* in_sizes, int n_in,
                              void* d_out, int out_size, void* d_ws, size_t ws_size,
                              hipStream_t stream) {
    const float* x     = (const float*)d_in[0];
    const int*   esrc  = (const int*)d_in[1];
    const int*   edst  = (const int*)d_in[2];
    const float* ea    = (const float*)d_in[3];
    const float* We    = (const float*)d_in[4];
    const float* be    = (const float*)d_in[5];
    const float* Wroot = (const float*)d_in[6];
    const float* bconv = (const float*)d_in[7];
    const float* gamma = (const float*)d_in[8];
    const float* beta  = (const float*)d_in[9];
    const float* Wlin  = (const float*)d_in[10];
    const float* blin  = (const float*)d_in[11];
    const float* Wq1   = (const float*)d_in[12];
    const float* bq1   = (const float*)d_in[13];
    const float* Wq2   = (const float*)d_in[14];
    const float* bq2   = (const float*)d_in[15];
    float* out = (float*)d_out;

    // workspace layout (bytes)
    char* ws = (char*)d_ws;
    int*   deg        = (int*)(ws + 0);          // 200704
    int*   cursor     = (int*)(ws + 200704);     // 200704
    int*   row_off    = (int*)(ws + 401408);     // 201728
    int*   partials   = (int*)(ws + 603136);     // 1024
    int*   poff       = (int*)(ws + 604160);     // 1024
    int*   epos       = (int*)(ws + 605184);     // 800768
    float* sorted_msg = (float*)(ws + 1405952);  // 25.6 MB
    float* featb      = (float*)(ws + 27005952); // 6.4 MB

    hipMemsetAsync(deg, 0, 2 * 200704, stream);  // deg + cursor (adjacent)

    hist_kernel<<<(NE + 255) / 256, 256, 0, stream>>>(edst, deg);
    partial_kernel<<<NPART, 256, 0, stream>>>(deg, partials);
    scan_partials_kernel<<<1, 256, 0, stream>>>(partials, poff);
    rowoff_kernel<<<NPART, 256, 0, stream>>>(deg, poff, row_off);
    build_pos_kernel<<<(NE + 255) / 256, 256, 0, stream>>>(edst, row_off, cursor, epos);
    edge_q4_kernel<<<(NE / 4 + 63) / 64, 256, 0, stream>>>(x, esrc, ea, We, be,
                                                           epos, sorted_msg);
    feat_kernel<<<(NN * 4 + 255) / 256, 256, 0, stream>>>(x, sorted_msg, row_off,
                                                          Wroot, bconv, gamma, beta,
                                                          Wlin, blin, featb);
    qhead_kernel<<<(NN / 2 * 4 + 255) / 256, 256, 0, stream>>>(featb, Wq1, bq1,
                                                               Wq2, bq2, out);
}

// Round 13
// 124.247 us; speedup vs baseline: 1.3357x; 1.3357x over previous
//
#include <hip/hip_runtime.h>

#define NN   50000
#define NE   200000
#define INC  16
#define HIDC 32
#define EDGED 8
#define OUTC 32
#define MLPH 128
#define NACT 32

#define NPART 196   // ceil(NN / 256)

typedef float floatx4 __attribute__((ext_vector_type(4)));

// ---- degree histogram ----
__global__ __launch_bounds__(256) void hist_kernel(const int* __restrict__ edst,
                                                   int* __restrict__ deg) {
    int e = blockIdx.x * blockDim.x + threadIdx.x;
    if (e < NE) atomicAdd(&deg[edst[e]], 1);
}

// ---- scan pass 1: per-block sums ----
__global__ __launch_bounds__(256) void partial_kernel(const int* __restrict__ deg,
                                                      int* __restrict__ partials) {
    __shared__ int sm[256];
    int t = threadIdx.x, i = blockIdx.x * 256 + t;
    sm[t] = (i < NN) ? deg[i] : 0;
    __syncthreads();
    #pragma unroll
    for (int off = 128; off > 0; off >>= 1) {
        if (t < off) sm[t] += sm[t + off];
        __syncthreads();
    }
    if (t == 0) partials[blockIdx.x] = sm[0];
}

// ---- scan pass 2: exclusive scan of 196 partials ----
__global__ __launch_bounds__(256) void scan_partials_kernel(const int* __restrict__ partials,
                                                            int* __restrict__ poff) {
    __shared__ int sm[256];
    int t = threadIdx.x;
    sm[t] = (t < NPART) ? partials[t] : 0;
    __syncthreads();
    for (int off = 1; off < 256; off <<= 1) {
        int v = (t >= off) ? sm[t - off] : 0;
        __syncthreads();
        sm[t] += v;
        __syncthreads();
    }
    poff[t] = (t == 0) ? 0 : sm[t - 1];
}

// ---- scan pass 3: block-local scan + base -> row_off ----
__global__ __launch_bounds__(256) void rowoff_kernel(const int* __restrict__ deg,
                                                     const int* __restrict__ poff,
                                                     int* __restrict__ row_off) {
    __shared__ int sm[256];
    int t = threadIdx.x, i = blockIdx.x * 256 + t;
    int d = (i < NN) ? deg[i] : 0;
    sm[t] = d;
    __syncthreads();
    for (int off = 1; off < 256; off <<= 1) {
        int v = (t >= off) ? sm[t - off] : 0;
        __syncthreads();
        sm[t] += v;
        __syncthreads();
    }
    int excl = sm[t] - d + poff[blockIdx.x];
    if (i < NN) {
        row_off[i] = excl;
        if (i == NN - 1) row_off[NN] = excl + d;   // == NE
    }
}

// ---- build position map: epos[e] = sorted position ----
__global__ __launch_bounds__(256) void build_pos_kernel(const int* __restrict__ edst,
                                                        const int* __restrict__ row_off,
                                                        int* __restrict__ cursor,
                                                        int* __restrict__ epos) {
    int e = blockIdx.x * blockDim.x + threadIdx.x;
    if (e < NE) {
        int dst = edst[e];
        epos[e] = row_off[dst] + atomicAdd(&cursor[dst], 1);
    }
}

// ---- edge kernel: quad per edge-PAIR, 2 edges/thread.
//      Live state ~52 regs (no spill). Lane l owns channels
//      {4l..4l+3, 16+4l..16+4l+3}; quad covers complete 64-B sectors.
//      Non-temporal stores: no RFO, no L2 pollution. ----
__global__ __launch_bounds__(256, 4) void edge_q2_kernel(
    const float* __restrict__ x,
    const int*   __restrict__ esrc,
    const float* __restrict__ ea,
    const float* __restrict__ We,        // [8][512] original layout
    const float* __restrict__ be,        // [512]
    const int*   __restrict__ epos,      // [NE] sorted position
    float*       __restrict__ sorted_msg) // [NE][32] dst-sorted rows
{
    __shared__ float sWe2[4 * 1032];  // [l][(i*8+cc)*8 + d]
    __shared__ float sbe2[4 * 132];   // [l][i*8+cc]
    int t = threadIdx.x;
    // destination-ordered staging: consecutive lanes -> consecutive words
    for (int idx = t; idx < 4 * 1032; idx += 256) {
        int l = idx / 1032, r = idx - l * 1032;
        float v = 0.f;
        if (r < 1024) {
            int d = r & 7, icc = r >> 3;
            int i = icc >> 3, cc = icc & 7;
            int h = ((cc & 4) << 2) + l * 4 + (cc & 3);   // channel
            v = We[d * 512 + i * 32 + h];
        }
        sWe2[idx] = v;
    }
    for (int idx = t; idx < 4 * 132; idx += 256) {
        int l = idx / 132, r = idx - l * 132;
        float v = 0.f;
        if (r < 128) {
            int i = r >> 3, cc = r & 7;
            int h = ((cc & 4) << 2) + l * 4 + (cc & 3);
            v = be[i * 32 + h];
        }
        sbe2[idx] = v;
    }
    __syncthreads();

    int q = blockIdx.x * 64 + (t >> 2);   // quad id = edge pair
    int l = t & 3;
    if (q >= NE / 2) return;

    int e0 = q, e1 = q + 100000;
    int s0 = esrc[e0], s1 = esrc[e1];
    int p0 = epos[e0], p1 = epos[e1];

    float ea0[8], ea1[8];
    {
        const float4* p;
        float4 a, b;
        p = reinterpret_cast<const float4*>(ea) + (size_t)e0 * 2; a = p[0]; b = p[1];
        ea0[0]=a.x; ea0[1]=a.y; ea0[2]=a.z; ea0[3]=a.w; ea0[4]=b.x; ea0[5]=b.y; ea0[6]=b.z; ea0[7]=b.w;
        p = reinterpret_cast<const float4*>(ea) + (size_t)e1 * 2; a = p[0]; b = p[1];
        ea1[0]=a.x; ea1[1]=a.y; ea1[2]=a.z; ea1[3]=a.w; ea1[4]=b.x; ea1[5]=b.y; ea1[6]=b.z; ea1[7]=b.w;
    }

    float m0[8], m1[8];
    #pragma unroll
    for (int c = 0; c < 8; ++c) { m0[c]=0.f; m1[c]=0.f; }

    const float* wl = sWe2 + l * 1032;
    const float* bl = sbe2 + l * 132;
    const float4* xp0 = reinterpret_cast<const float4*>(x) + (size_t)s0 * 4;
    const float4* xp1 = reinterpret_cast<const float4*>(x) + (size_t)s1 * 4;

    for (int i4 = 0; i4 < 4; ++i4) {        // rolled: keeps code I$-sized
        float4 xv0 = xp0[i4], xv1 = xp1[i4];
        float xs0[4] = {xv0.x, xv0.y, xv0.z, xv0.w};
        float xs1[4] = {xv1.x, xv1.y, xv1.z, xv1.w};
        const float* wb4 = wl + i4 * 256;
        const float* bb4 = bl + i4 * 32;
        #pragma unroll
        for (int ii = 0; ii < 4; ++ii) {
            const float* wbase = wb4 + ii * 64;
            const float* bbase = bb4 + ii * 8;
            float xi0 = xs0[ii], xi1 = xs1[ii];
            #pragma unroll
            for (int cc = 0; cc < 8; ++cc) {
                const float* wr = wbase + cc * 8;
                float bv = bbase[cc];
                float w0 = bv, w1 = bv;
                #pragma unroll
                for (int d = 0; d < 8; ++d) {
                    float wd = wr[d];
                    w0 = fmaf(ea0[d], wd, w0);
                    w1 = fmaf(ea1[d], wd, w1);
                }
                w0 = fmaxf(w0, 0.f); w1 = fmaxf(w1, 0.f);
                m0[cc] = fmaf(xi0, w0, m0[cc]);
                m1[cc] = fmaf(xi1, w1, m1[cc]);
            }
        }
    }

    // slots 0..3 -> float offset l*4; slots 4..7 -> 16+l*4 (second sector)
    floatx4* o;
    floatx4 v;
    o = reinterpret_cast<floatx4*>(sorted_msg + (size_t)p0 * 32 + l * 4);
    v = (floatx4){m0[0], m0[1], m0[2], m0[3]};
    __builtin_nontemporal_store(v, o);
    v = (floatx4){m0[4], m0[5], m0[6], m0[7]};
    __builtin_nontemporal_store(v, o + 4);
    o = reinterpret_cast<floatx4*>(sorted_msg + (size_t)p1 * 32 + l * 4);
    v = (floatx4){m1[0], m1[1], m1[2], m1[3]};
    __builtin_nontemporal_store(v, o);
    v = (floatx4){m1[4], m1[5], m1[6], m1[7]};
    __builtin_nontemporal_store(v, o + 4);
}

// ---- feat kernel: 4 lanes/node; CONTIGUOUS sorted_msg stream.
//      Lane l owns channels {4l..4l+3, 16+4l..16+4l+3}. ----
__global__ __launch_bounds__(256, 4) void feat_kernel(
    const float* __restrict__ x,
    const float* __restrict__ sorted_msg,  // [NE][32] dst-sorted
    const int*   __restrict__ row_off,
    const float* __restrict__ Wroot,   // [16][32]
    const float* __restrict__ bconv,
    const float* __restrict__ gamma,
    const float* __restrict__ beta,
    const float* __restrict__ Wlin,    // [32][32]
    const float* __restrict__ blin,
    float* __restrict__ feat)          // [NN][32]
{
    int tid = blockIdx.x * 256 + threadIdx.x;
    int n = tid >> 2;
    int l = tid & 3;
    if (n >= NN) return;
    int o1 = l * 4;        // float offset of first slice
    int o2 = 16 + l * 4;   // float offset of second slice

    float h8[8];
    {
        const float4 a = *reinterpret_cast<const float4*>(bconv + o1);
        const float4 b = *reinterpret_cast<const float4*>(bconv + o2);
        h8[0]=a.x; h8[1]=a.y; h8[2]=a.z; h8[3]=a.w;
        h8[4]=b.x; h8[5]=b.y; h8[6]=b.z; h8[7]=b.w;
    }

    int start = row_off[n], end = row_off[n + 1];
    for (int k = start; k < end; ++k) {
        const float* row = sorted_msg + (size_t)k * 32;
        float4 a = *reinterpret_cast<const float4*>(row + o1);
        float4 b = *reinterpret_cast<const float4*>(row + o2);
        h8[0]+=a.x; h8[1]+=a.y; h8[2]+=a.z; h8[3]+=a.w;
        h8[4]+=b.x; h8[5]+=b.y; h8[6]+=b.z; h8[7]+=b.w;
    }

    const float4* x4 = reinterpret_cast<const float4*>(x) + (size_t)n * 4;
    #pragma unroll
    for (int i4 = 0; i4 < 4; ++i4) {
        float4 xv = x4[i4];
        float xsub[4] = {xv.x, xv.y, xv.z, xv.w};
        #pragma unroll
        for (int ii = 0; ii < 4; ++ii) {
            const float* wr = Wroot + (i4 * 4 + ii) * HIDC;
            float4 a = *reinterpret_cast<const float4*>(wr + o1);
            float4 b = *reinterpret_cast<const float4*>(wr + o2);
            float xi = xsub[ii];
            h8[0]=fmaf(xi,a.x,h8[0]); h8[1]=fmaf(xi,a.y,h8[1]);
            h8[2]=fmaf(xi,a.z,h8[2]); h8[3]=fmaf(xi,a.w,h8[3]);
            h8[4]=fmaf(xi,b.x,h8[4]); h8[5]=fmaf(xi,b.y,h8[5]);
            h8[6]=fmaf(xi,b.z,h8[6]); h8[7]=fmaf(xi,b.w,h8[7]);
        }
    }

    // LayerNorm (quad butterfly on scalars) + ReLU
    float s = ((h8[0]+h8[1])+(h8[2]+h8[3])) + ((h8[4]+h8[5])+(h8[6]+h8[7]));
    s += __shfl_xor(s, 1);
    s += __shfl_xor(s, 2);
    float mu = s * (1.f / HIDC);
    float v = 0.f;
    #pragma unroll
    for (int c = 0; c < 8; ++c) { float d = h8[c] - mu; v = fmaf(d, d, v); }
    v += __shfl_xor(v, 1);
    v += __shfl_xor(v, 2);
    float rstd = rsqrtf(v * (1.f / HIDC) + 1e-5f);
    {
        float4 g0 = *reinterpret_cast<const float4*>(gamma + o1);
        float4 g1 = *reinterpret_cast<const float4*>(gamma + o2);
        float4 b0 = *reinterpret_cast<const float4*>(beta + o1);
        float4 b1 = *reinterpret_cast<const float4*>(beta + o2);
        float gs[8] = {g0.x,g0.y,g0.z,g0.w,g1.x,g1.y,g1.z,g1.w};
        float bs[8] = {b0.x,b0.y,b0.z,b0.w,b1.x,b1.y,b1.z,b1.w};
        #pragma unroll
        for (int c = 0; c < 8; ++c)
            h8[c] = fmaxf(fmaf((h8[c] - mu) * rstd, gs[c], bs[c]), 0.f);
    }

    // feat slices: broadcast h via width-4 shuffles; k = (c>>2)*16+srcl*4+(c&3)
    float f8[8];
    {
        float4 a = *reinterpret_cast<const float4*>(blin + o1);
        float4 b = *reinterpret_cast<const float4*>(blin + o2);
        f8[0]=a.x; f8[1]=a.y; f8[2]=a.z; f8[3]=a.w;
        f8[4]=b.x; f8[5]=b.y; f8[6]=b.z; f8[7]=b.w;
    }
    #pragma unroll
    for (int srcl = 0; srcl < 4; ++srcl) {
        #pragma unroll
        for (int c = 0; c < 8; ++c) {
            float hv = __shfl(h8[c], srcl, 4);
            int k = ((c & 4) << 2) + srcl * 4 + (c & 3);   // channel of h8[c]@srcl
            const float* wr = Wlin + k * OUTC;
            float4 a = *reinterpret_cast<const float4*>(wr + o1);
            float4 b = *reinterpret_cast<const float4*>(wr + o2);
            f8[0]=fmaf(hv,a.x,f8[0]); f8[1]=fmaf(hv,a.y,f8[1]);
            f8[2]=fmaf(hv,a.z,f8[2]); f8[3]=fmaf(hv,a.w,f8[3]);
            f8[4]=fmaf(hv,b.x,f8[4]); f8[5]=fmaf(hv,b.y,f8[5]);
            f8[6]=fmaf(hv,b.z,f8[6]); f8[7]=fmaf(hv,b.w,f8[7]);
        }
    }

    float* orow = feat + (size_t)n * OUTC;
    *reinterpret_cast<float4*>(orow + o1) = make_float4(f8[0], f8[1], f8[2], f8[3]);
    *reinterpret_cast<float4*>(orow + o2) = make_float4(f8[4], f8[5], f8[6], f8[7]);
}

// ---- q_head: quad per node-pair, 2 nodes/thread ----
__global__ __launch_bounds__(256, 3) void qhead_kernel(
    const float* __restrict__ feat,    // [NN][32]
    const float* __restrict__ Wq1,     // [32][128] original layout
    const float* __restrict__ bq1,
    const float* __restrict__ Wq2,     // [128][32]
    const float* __restrict__ bq2,
    float* __restrict__ out)
{
    __shared__ float sw1[4 * 1032];    // [l][k*32+j], stagger 1032
    int t = threadIdx.x;
    for (int w = t; w < 4096; w += 256) {
        int k = w >> 7, m = w & 127, l = m >> 5, j = m & 31;
        sw1[l * 1032 + k * 32 + j] = Wq1[w];
    }
    __syncthreads();

    int gid = blockIdx.x * 256 + t;
    int p = gid >> 2;
    int l = gid & 3;
    if (p >= NN / 2) return;
    int n0 = p * 2, n1 = p * 2 + 1;

    float f0[OUTC], f1[OUTC];
    {
        const float4* a4 = reinterpret_cast<const float4*>(feat + (size_t)n0 * 32);
        const float4* b4 = reinterpret_cast<const float4*>(feat + (size_t)n1 * 32);
        #pragma unroll
        for (int i = 0; i < 8; ++i) {
            float4 a = a4[i], b = b4[i];
            f0[i*4+0]=a.x; f0[i*4+1]=a.y; f0[i*4+2]=a.z; f0[i*4+3]=a.w;
            f1[i*4+0]=b.x; f1[i*4+1]=b.y; f1[i*4+2]=b.z; f1[i*4+3]=b.w;
        }
    }

    float acc0[32], acc1[32];
    {
        const float4* b4 = reinterpret_cast<const float4*>(bq1 + l * 32);
        #pragma unroll
        for (int j4 = 0; j4 < 8; ++j4) {
            float4 b = b4[j4];
            acc0[j4*4+0]=b.x; acc0[j4*4+1]=b.y; acc0[j4*4+2]=b.z; acc0[j4*4+3]=b.w;
            acc1[j4*4+0]=b.x; acc1[j4*4+1]=b.y; acc1[j4*4+2]=b.z; acc1[j4*4+3]=b.w;
        }
    }
    const float* w1 = sw1 + l * 1032;
    #pragma unroll
    for (int k = 0; k < 32; ++k) {
        float fk0 = f0[k], fk1 = f1[k];
        const float* wr = w1 + k * 32;
        #pragma unroll
        for (int j = 0; j < 32; ++j) {
            float wj = wr[j];
            acc0[j] = fmaf(fk0, wj, acc0[j]);
            acc1[j] = fmaf(fk1, wj, acc1[j]);
        }
    }
    #pragma unroll
    for (int j = 0; j < 32; ++j) {
        acc0[j] = fmaxf(acc0[j], 0.f);
        acc1[j] = fmaxf(acc1[j], 0.f);
    }

    float q0[8], q1[8];
    {
        const float4* b4 = reinterpret_cast<const float4*>(bq2 + l * 8);
        float4 a = b4[0], b = b4[1];
        q0[0]=a.x; q0[1]=a.y; q0[2]=a.z; q0[3]=a.w;
        q0[4]=b.x; q0[5]=b.y; q0[6]=b.z; q0[7]=b.w;
        #pragma unroll
        for (int c = 0; c < 8; ++c) q1[c] = q0[c];
    }
    #pragma unroll
    for (int srcl = 0; srcl < 4; ++srcl) {
        #pragma unroll
        for (int j = 0; j < 32; ++j) {
            float a0 = __shfl(acc0[j], srcl, 4);
            float a1 = __shfl(acc1[j], srcl, 4);
            int m = srcl * 32 + j;
            const float4* w2 = reinterpret_cast<const float4*>(Wq2 + m * NACT + l * 8);
            float4 wa = w2[0], wb = w2[1];
            q0[0]=fmaf(a0,wa.x,q0[0]); q0[1]=fmaf(a0,wa.y,q0[1]);
            q0[2]=fmaf(a0,wa.z,q0[2]); q0[3]=fmaf(a0,wa.w,q0[3]);
            q0[4]=fmaf(a0,wb.x,q0[4]); q0[5]=fmaf(a0,wb.y,q0[5]);
            q0[6]=fmaf(a0,wb.z,q0[6]); q0[7]=fmaf(a0,wb.w,q0[7]);
            q1[0]=fmaf(a1,wa.x,q1[0]); q1[1]=fmaf(a1,wa.y,q1[1]);
            q1[2]=fmaf(a1,wa.z,q1[2]); q1[3]=fmaf(a1,wa.w,q1[3]);
            q1[4]=fmaf(a1,wb.x,q1[4]); q1[5]=fmaf(a1,wb.y,q1[5]);
            q1[6]=fmaf(a1,wb.z,q1[6]); q1[7]=fmaf(a1,wb.w,q1[7]);
        }
    }

    float4* o;
    o = reinterpret_cast<float4*>(out + (size_t)n0 * NACT + l * 8);
    o[0] = make_float4(q0[0], q0[1], q0[2], q0[3]);
    o[1] = make_float4(q0[4], q0[5], q0[6], q0[7]);
    o = reinterpret_cast<float4*>(out + (size_t)n1 * NACT + l * 8);
    o[0] = make_float4(q1[0], q1[1], q1[2], q1[3]);
    o[1] = make_float4(q1[4], q1[5], q1[6], q1[7]);
}

extern "C" void kernel_launch(void* const* d_in, const int* in_sizes, int n_in,
                              void* d_out, int out_size, void* d_ws, size_t ws_size,
                              hipStream_t stream) {
    const float* x     = (const float*)d_in[0];
    const int*   esrc  = (const int*)d_in[1];
    const int*   edst  = (const int*)d_in[2];
    const float* ea    = (const float*)d_in[3];
    const float* We    = (const float*)d_in[4];
    const float* be    = (const float*)d_in[5];
    const float* Wroot = (const float*)d_in[6];
    const float* bconv = (const float*)d_in[7];
    const float* gamma = (const float*)d_in[8];
    const float* beta  = (const float*)d_in[9];
    const float* Wlin  = (const float*)d_in[10];
    const float* blin  = (const float*)d_in[11];
    const float* Wq1   = (const float*)d_in[12];
    const float* bq1   = (const float*)d_in[13];
    const float* Wq2   = (const float*)d_in[14];
    const float* bq2   = (const float*)d_in[15];
    float* out = (float*)d_out;

    // workspace layout (bytes)
    char* ws = (char*)d_ws;
    int*   deg        = (int*)(ws + 0);          // 200704
    int*   cursor     = (int*)(ws + 200704);     // 200704
    int*   row_off    = (int*)(ws + 401408);     // 201728
    int*   partials   = (int*)(ws + 603136);     // 1024
    int*   poff       = (int*)(ws + 604160);     // 1024
    int*   epos       = (int*)(ws + 605184);     // 800768
    float* sorted_msg = (float*)(ws + 1405952);  // 25.6 MB
    float* featb      = (float*)(ws + 27005952); // 6.4 MB

    hipMemsetAsync(deg, 0, 2 * 200704, stream);  // deg + cursor (adjacent)

    hist_kernel<<<(NE + 255) / 256, 256, 0, stream>>>(edst, deg);
    partial_kernel<<<NPART, 256, 0, stream>>>(deg, partials);
    scan_partials_kernel<<<1, 256, 0, stream>>>(partials, poff);
    rowoff_kernel<<<NPART, 256, 0, stream>>>(deg, poff, row_off);
    build_pos_kernel<<<(NE + 255) / 256, 256, 0, stream>>>(edst, row_off, cursor, epos);
    edge_q2_kernel<<<(NE / 2 * 4 + 255) / 256, 256, 0, stream>>>(x, esrc, ea, We, be,
                                                                 epos, sorted_msg);
    feat_kernel<<<(NN * 4 + 255) / 256, 256, 0, stream>>>(x, sorted_msg, row_off,
                                                          Wroot, bconv, gamma, beta,
                                                          Wlin, blin, featb);
    qhead_kernel<<<(NN / 2 * 4 + 255) / 256, 256, 0, stream>>>(featb, Wq1, bq1,
                                                               Wq2, bq2, out);
}